// Round 1
// baseline (645.545 us; speedup 1.0000x reference)
//
#include <hip/hip_runtime.h>

// Problem constants
//   INP=4096 MSK=64 HID=64 OUT=10  L1=64 L2=256 L3=128  B=16384  WVEC=4810
// Inputs: data(B*4096 f32), mask_idx(B*64 i32), W1(64x4096), b1(64),
//         W2(256x64), b2(256), W3(128x256), b3(128), W4(4810x128), b4(4810)
// Output: res (B*10 f32)
// ws usage: W1T 262144 f + xm 1048576 f + h3 2097152 f = ~13.6 MB

// ---------------------------------------------------------------- prep: W1^T
__global__ __launch_bounds__(256) void k_prep(const float* __restrict__ W1,
                                              float* __restrict__ W1T) {
    // W1T[j*64+i] = W1[i*4096+j]
    for (int e = blockIdx.x * 256 + threadIdx.x; e < 4096 * 64; e += 256 * 256) {
        int j = e >> 6, i = e & 63;
        W1T[e] = W1[(size_t)i * 4096 + j];
    }
}

// ------------------------------------------------- steps 1-4: gather + MLP
__global__ __launch_bounds__(256) void k_mlp(
    const float* __restrict__ data, const int* __restrict__ midx,
    const float* __restrict__ W1T, const float* __restrict__ b1,
    const float* __restrict__ W2, const float* __restrict__ b2,
    const float* __restrict__ W3, const float* __restrict__ b3,
    float* __restrict__ xm_out, float* __restrict__ h3_out)
{
    __shared__ int   idx_s[64 * 64];
    __shared__ __align__(16) float h1_s[64 * 64];
    __shared__ __align__(16) float h2_s[64 * 256];

    const int t = threadIdx.x;
    const int row0 = blockIdx.x * 64;

    for (int e = t; e < 64 * 64; e += 256)
        idx_s[e] = midx[(size_t)row0 * 64 + e];
    __syncthreads();

    const int w = t >> 6, lane = t & 63;

    // ---- xm gather + layer 1 (dedup via sorted adjacent-equal skip)
    const float b1v = b1[lane];
    for (int rr = 0; rr < 16; ++rr) {
        const int r = w * 16 + rr;
        const size_t grow = (size_t)(row0 + r);
        const int gid = idx_s[r * 64 + lane];
        xm_out[grow * 64 + lane] = data[grow * 4096 + gid];

        float acc = b1v;
        int prev = -1;
        for (int i = 0; i < 64; ++i) {
            int cur = idx_s[r * 64 + i];
            float wv = W1T[cur * 64 + lane];
            acc += (cur != prev) ? wv : 0.0f;   // mask uses .set -> dedupe
            prev = cur;
        }
        h1_s[r * 64 + lane] = fmaxf(acc, 0.0f);
    }
    // wave-local rows only -> no barrier needed between layers

    // ---- layer 2: 64 -> 256
    for (int c = 0; c < 4; ++c) {
        const int o = c * 64 + lane;
        float acc[16];
        const float bb = b2[o];
        #pragma unroll
        for (int rr = 0; rr < 16; ++rr) acc[rr] = bb;
        for (int k4 = 0; k4 < 16; ++k4) {
            const float4 wv = *(const float4*)&W2[o * 64 + k4 * 4];
            #pragma unroll
            for (int rr = 0; rr < 16; ++rr) {
                const float4 h4 = *(const float4*)&h1_s[(w * 16 + rr) * 64 + k4 * 4];
                acc[rr] += h4.x * wv.x + h4.y * wv.y + h4.z * wv.z + h4.w * wv.w;
            }
        }
        #pragma unroll
        for (int rr = 0; rr < 16; ++rr)
            h2_s[(w * 16 + rr) * 256 + o] = fmaxf(acc[rr], 0.0f);
    }

    // ---- layer 3: 256 -> 128
    for (int c = 0; c < 2; ++c) {
        const int o = c * 64 + lane;
        float acc[16];
        const float bb = b3[o];
        #pragma unroll
        for (int rr = 0; rr < 16; ++rr) acc[rr] = bb;
        for (int k4 = 0; k4 < 64; ++k4) {
            const float4 wv = *(const float4*)&W3[o * 256 + k4 * 4];
            #pragma unroll
            for (int rr = 0; rr < 16; ++rr) {
                const float4 h4 = *(const float4*)&h2_s[(w * 16 + rr) * 256 + k4 * 4];
                acc[rr] += h4.x * wv.x + h4.y * wv.y + h4.z * wv.z + h4.w * wv.w;
            }
        }
        #pragma unroll
        for (int rr = 0; rr < 16; ++rr)
            h3_out[(size_t)(row0 + w * 16 + rr) * 128 + o] = fmaxf(acc[rr], 0.0f);
    }
}

// -------------------------- steps 5+8+9: fused W4 GEMM + per-sample network
// Chunk c covers W4 rows [64c, 64c+64):
//   c in [0,64)  : inp_w slice h=c  -> hid_s[r][c] = sum_m (C+b4)*xm
//   c == 64     : inp_b            -> hid_s[r][h] += C+b4 ; then ReLU
//   c in [65,75): out_w slice o=c-65 -> res_s[r][o] = sum_h (C+b4)*hid
//   c == 75     : out_b (10 rows)  -> res_s[r][o] += C+b4
__global__ __launch_bounds__(256) void k_hyper(
    const float* __restrict__ xmg, const float* __restrict__ h3g,
    const float* __restrict__ W4, const float* __restrict__ b4,
    float* __restrict__ out)
{
    __shared__ __align__(16) float h3_s[64 * 132];   // stride 132 pad
    __shared__ __align__(16) float w4_s[64 * 132];
    __shared__ float xm_s[64 * 65];
    __shared__ float hid_s[64 * 65];
    __shared__ float res_s[64 * 10];

    const int t = threadIdx.x;
    const int tn = t & 15;        // n/m sub-index (reduction group, in-wave)
    const int tr = t >> 4;        // r sub-index
    const int row0 = blockIdx.x * 64;

    // stage h3 tile
    for (int e = t; e < 64 * 32; e += 256) {
        int r = e >> 5, q = e & 31;
        *(float4*)&h3_s[r * 132 + q * 4] =
            *(const float4*)&h3g[(size_t)(row0 + r) * 128 + q * 4];
    }
    // stage xm tile
    for (int e = t; e < 64 * 64; e += 256) {
        int r = e >> 6, m = e & 63;
        xm_s[r * 65 + m] = xmg[(size_t)(row0 + r) * 64 + m];
    }
    // stage W4 chunk 0
    #pragma unroll
    for (int q = 0; q < 8; ++q) {
        int u = q * 256 + t, n = u >> 5, k4 = u & 31;
        *(float4*)&w4_s[n * 132 + k4 * 4] = *(const float4*)&W4[(size_t)n * 128 + k4 * 4];
    }
    __syncthreads();

    for (int c = 0; c <= 75; ++c) {
        // prefetch next W4 chunk into registers (latency hidden under compute)
        float4 nxt[8];
        if (c < 75) {
            #pragma unroll
            for (int q = 0; q < 8; ++q) {
                int u = q * 256 + t, n = u >> 5, k4 = u & 31;
                int ng = (c + 1) * 64 + n;
                nxt[q] = (ng < 4810) ? *(const float4*)&W4[(size_t)ng * 128 + k4 * 4]
                                     : make_float4(0.f, 0.f, 0.f, 0.f);
            }
        }

        // C[n=64c+tn+16i][r=tr+16j] : 4x4 register tile, K=128
        float acc[4][4];
        #pragma unroll
        for (int i = 0; i < 4; ++i)
            #pragma unroll
            for (int j = 0; j < 4; ++j) acc[i][j] = 0.f;

        #pragma unroll 2
        for (int k4 = 0; k4 < 32; ++k4) {
            float4 a[4], b[4];
            #pragma unroll
            for (int i = 0; i < 4; ++i)
                a[i] = *(const float4*)&w4_s[(tn + 16 * i) * 132 + k4 * 4];
            #pragma unroll
            for (int j = 0; j < 4; ++j)
                b[j] = *(const float4*)&h3_s[(tr + 16 * j) * 132 + k4 * 4];
            #pragma unroll
            for (int i = 0; i < 4; ++i)
                #pragma unroll
                for (int j = 0; j < 4; ++j)
                    acc[i][j] += a[i].x * b[j].x + a[i].y * b[j].y +
                                 a[i].z * b[j].z + a[i].w * b[j].w;
        }

        float bv[4];
        #pragma unroll
        for (int i = 0; i < 4; ++i) {
            int ng = c * 64 + tn + 16 * i;
            bv[i] = (ng < 4810) ? b4[ng] : 0.f;
        }

        if (c < 64) {                       // inp_w slice h=c
            #pragma unroll
            for (int j = 0; j < 4; ++j) {
                const int r = tr + 16 * j;
                float s = 0.f;
                #pragma unroll
                for (int i = 0; i < 4; ++i)
                    s += (acc[i][j] + bv[i]) * xm_s[r * 65 + tn + 16 * i];
                #pragma unroll
                for (int off = 8; off; off >>= 1) s += __shfl_xor(s, off);
                if (tn == 0) hid_s[r * 65 + c] = s;
            }
        } else if (c == 64) {               // inp_b
            #pragma unroll
            for (int i = 0; i < 4; ++i)
                #pragma unroll
                for (int j = 0; j < 4; ++j)
                    hid_s[(tr + 16 * j) * 65 + tn + 16 * i] += acc[i][j] + bv[i];
        } else if (c < 75) {                // out_w slice o=c-65
            const int o = c - 65;
            #pragma unroll
            for (int j = 0; j < 4; ++j) {
                const int r = tr + 16 * j;
                float s = 0.f;
                #pragma unroll
                for (int i = 0; i < 4; ++i)
                    s += (acc[i][j] + bv[i]) * hid_s[r * 65 + tn + 16 * i];
                #pragma unroll
                for (int off = 8; off; off >>= 1) s += __shfl_xor(s, off);
                if (tn == 0) res_s[r * 10 + o] = s;
            }
        } else {                            // out_b (rows 4800..4809)
            if (tn < 10) {
                #pragma unroll
                for (int j = 0; j < 4; ++j)
                    res_s[(tr + 16 * j) * 10 + tn] += acc[0][j] + bv[0];
            }
        }
        __syncthreads();

        // commit prefetched chunk to LDS
        if (c < 75) {
            #pragma unroll
            for (int q = 0; q < 8; ++q) {
                int u = q * 256 + t, n = u >> 5, k4 = u & 31;
                *(float4*)&w4_s[n * 132 + k4 * 4] = nxt[q];
            }
        }
        if (c == 64) {                      // ReLU hid before out_w chunks
            for (int e = t; e < 64 * 64; e += 256) {
                int r = e >> 6, h = e & 63;
                hid_s[r * 65 + h] = fmaxf(hid_s[r * 65 + h], 0.f);
            }
        }
        __syncthreads();
    }

    for (int e = t; e < 640; e += 256)
        out[(size_t)row0 * 10 + e] = res_s[e];
}

// ---------------------------------------------------------------- launcher
extern "C" void kernel_launch(void* const* d_in, const int* in_sizes, int n_in,
                              void* d_out, int out_size, void* d_ws, size_t ws_size,
                              hipStream_t stream)
{
    const float* data = (const float*)d_in[0];
    const int*   midx = (const int*)d_in[1];
    const float* W1   = (const float*)d_in[2];
    const float* b1   = (const float*)d_in[3];
    const float* W2   = (const float*)d_in[4];
    const float* b2   = (const float*)d_in[5];
    const float* W3   = (const float*)d_in[6];
    const float* b3   = (const float*)d_in[7];
    const float* W4   = (const float*)d_in[8];
    const float* b4   = (const float*)d_in[9];
    float* out = (float*)d_out;

    float* W1T   = (float*)d_ws;                        // 4096*64
    float* xm_ws = W1T + 4096 * 64;                     // 16384*64
    float* h3_ws = xm_ws + (size_t)16384 * 64;          // 16384*128

    k_prep <<<256, 256, 0, stream>>>(W1, W1T);
    k_mlp  <<<256, 256, 0, stream>>>(data, midx, W1T, b1, W2, b2, W3, b3, xm_ws, h3_ws);
    k_hyper<<<256, 256, 0, stream>>>(xm_ws, h3_ws, W4, b4, out);
}

// Round 2
// 295.098 us; speedup vs baseline: 2.1876x; 2.1876x over previous
//
#include <hip/hip_runtime.h>

// INP=4096 MSK=64 HID=64 OUT=10  L1=64 L2=256 L3=128  B=16384  WVEC=4810
// Strategy: step-5 GEMM (w = h3 @ W4^T) in f16 MFMA with A (W4) straight from
// L2, B (h3) resident in VGPR fragments; per-sample einsums fused as f32
// register epilogues. b4 stays f32 throughout.

typedef _Float16 f16;
typedef _Float16 f16x8 __attribute__((ext_vector_type(8)));
typedef float    f32x4 __attribute__((ext_vector_type(4)));

#define NPAD 4864   // 4810 W4 rows padded to 76*64

// ---------------------------------------------------------------- prep
__global__ __launch_bounds__(256) void k_prep(const float* __restrict__ W1,
                                              const float* __restrict__ W4,
                                              float* __restrict__ W1T,
                                              f16* __restrict__ W4h) {
    const int tid = blockIdx.x * 256 + threadIdx.x;
    const int stride = gridDim.x * 256;
    for (int e = tid; e < 4096 * 64; e += stride) {
        int j = e >> 6, i = e & 63;
        W1T[e] = W1[(size_t)i * 4096 + j];
    }
    for (int e = tid; e < NPAD * 128; e += stride) {
        int n = e >> 7;
        W4h[e] = (n < 4810) ? (f16)W4[e] : (f16)0.f;
    }
}

// ------------------------------------------------- steps 1-4: gather + MLP
// 32 rows/block, grid 512 -> LDS ~49KB -> 2+ blocks/CU (was 1 at 98KB)
__global__ __launch_bounds__(256) void k_mlp(
    const float* __restrict__ data, const int* __restrict__ midx,
    const float* __restrict__ W1T, const float* __restrict__ b1,
    const float* __restrict__ W2, const float* __restrict__ b2,
    const float* __restrict__ W3, const float* __restrict__ b3,
    float* __restrict__ xm_out, f16* __restrict__ h3_out)
{
    __shared__ int   idx_s[32 * 64];
    __shared__ __align__(16) float h1_s[32 * 64];
    __shared__ __align__(16) float h2_s[32 * 256];

    const int t = threadIdx.x;
    const int row0 = blockIdx.x * 32;

    for (int e = t; e < 32 * 64; e += 256)
        idx_s[e] = midx[(size_t)row0 * 64 + e];
    __syncthreads();

    const int w = t >> 6, lane = t & 63;

    // ---- xm gather + layer 1 (dedup via sorted adjacent-equal skip)
    const float b1v = b1[lane];
    for (int rr = 0; rr < 8; ++rr) {
        const int r = w * 8 + rr;
        const size_t grow = (size_t)(row0 + r);
        const int gid = idx_s[r * 64 + lane];
        xm_out[grow * 64 + lane] = data[grow * 4096 + gid];

        float acc = b1v;
        int prev = -1;
        for (int i = 0; i < 64; ++i) {
            int cur = idx_s[r * 64 + i];
            float wv = W1T[cur * 64 + lane];
            acc += (cur != prev) ? wv : 0.0f;   // mask uses .set -> dedupe
            prev = cur;
        }
        h1_s[r * 64 + lane] = fmaxf(acc, 0.0f);
    }

    // ---- layer 2: 64 -> 256
    for (int c = 0; c < 4; ++c) {
        const int o = c * 64 + lane;
        float acc[8];
        const float bb = b2[o];
        #pragma unroll
        for (int rr = 0; rr < 8; ++rr) acc[rr] = bb;
        for (int k4 = 0; k4 < 16; ++k4) {
            const float4 wv = *(const float4*)&W2[o * 64 + k4 * 4];
            #pragma unroll
            for (int rr = 0; rr < 8; ++rr) {
                const float4 h4 = *(const float4*)&h1_s[(w * 8 + rr) * 64 + k4 * 4];
                acc[rr] += h4.x * wv.x + h4.y * wv.y + h4.z * wv.z + h4.w * wv.w;
            }
        }
        #pragma unroll
        for (int rr = 0; rr < 8; ++rr)
            h2_s[(w * 8 + rr) * 256 + o] = fmaxf(acc[rr], 0.0f);
    }

    // ---- layer 3: 256 -> 128 (h3 written as f16 for MFMA B-operand)
    for (int c = 0; c < 2; ++c) {
        const int o = c * 64 + lane;
        float acc[8];
        const float bb = b3[o];
        #pragma unroll
        for (int rr = 0; rr < 8; ++rr) acc[rr] = bb;
        for (int k4 = 0; k4 < 64; ++k4) {
            const float4 wv = *(const float4*)&W3[o * 256 + k4 * 4];
            #pragma unroll
            for (int rr = 0; rr < 8; ++rr) {
                const float4 h4 = *(const float4*)&h2_s[(w * 8 + rr) * 256 + k4 * 4];
                acc[rr] += h4.x * wv.x + h4.y * wv.y + h4.z * wv.z + h4.w * wv.w;
            }
        }
        #pragma unroll
        for (int rr = 0; rr < 8; ++rr)
            h3_out[(size_t)(row0 + w * 8 + rr) * 128 + o] = (f16)fmaxf(acc[rr], 0.0f);
    }
}

// -------------------------- steps 5+8+9: MFMA W4 GEMM + register epilogues
// Block: 32 samples, 512 thr, 8 waves = (rw in 0..1 sample-group) x (cw in
// 0..3 chunk-group). Wave (rw,cw): all 64 m x 16 samples x chunks {c%4==cw}.
// D layout (m89): col = lane&15 (sample), row = 4*(lane>>4)+reg (+16*mt).
__global__ __launch_bounds__(512, 4) void k_hyper(
    const float* __restrict__ xmg, const f16* __restrict__ h3h,
    const f16* __restrict__ W4h, const float* __restrict__ b4,
    float* __restrict__ out)
{
    __shared__ __align__(16) float b4_s[NPAD];
    __shared__ __align__(16) float hid_s[32 * 68];
    __shared__ __align__(16) float res_s[32 * 12];

    const int t = threadIdx.x;
    const int w = t >> 6;
    const int lane = t & 63;
    const int rw = w >> 2;          // sample group
    const int cw = w & 3;           // chunk group
    const int lr = lane & 15;
    const int g  = lane >> 4;       // k-group / m-subgroup
    const int r_local = lr + 16 * rw;
    const int row0 = blockIdx.x * 32;
    const size_t grow = (size_t)(row0 + r_local);

    for (int i = t; i < NPAD; i += 512)
        b4_s[i] = (i < 4810) ? b4[i] : 0.f;

    // B-fragments (h3, chunk-invariant): lane holds h3[r_local][32kk+8g .. +8]
    f16x8 bfrag[4];
    #pragma unroll
    for (int kk = 0; kk < 4; ++kk)
        bfrag[kk] = *(const f16x8*)&h3h[grow * 128 + 32 * kk + 8 * g];

    // xm registers: xm[r_local][16mt+4g .. +4]
    f32x4 xmr[4];
    #pragma unroll
    for (int mt = 0; mt < 4; ++mt)
        xmr[mt] = *(const f32x4*)&xmg[grow * 64 + 16 * mt + 4 * g];

    __syncthreads();   // b4_s ready

    const f32x4 zero = {0.f, 0.f, 0.f, 0.f};

    // ---------------- inp_w chunks: c = cw + 4j -> hid_s[r][c]
    for (int j = 0; j < 16; ++j) {
        const int c = cw + 4 * j;
        const f16* Ab = W4h + (size_t)(64 * c) * 128;
        f16x8 a[4][4];                       // [kk][mt]
        #pragma unroll
        for (int mt = 0; mt < 4; ++mt)
            a[0][mt] = *(const f16x8*)&Ab[(16 * mt + lr) * 128 + 8 * g];
        #pragma unroll
        for (int mt = 0; mt < 4; ++mt)
            a[1][mt] = *(const f16x8*)&Ab[(16 * mt + lr) * 128 + 32 + 8 * g];
        f32x4 acc[4] = {zero, zero, zero, zero};
        #pragma unroll
        for (int kk = 0; kk < 4; ++kk) {
            if (kk < 2) {
                #pragma unroll
                for (int mt = 0; mt < 4; ++mt)
                    a[kk + 2][mt] = *(const f16x8*)&Ab[(16 * mt + lr) * 128 + 32 * (kk + 2) + 8 * g];
            }
            #pragma unroll
            for (int mt = 0; mt < 4; ++mt)
                acc[mt] = __builtin_amdgcn_mfma_f32_16x16x32_f16(a[kk][mt], bfrag[kk], acc[mt], 0, 0, 0);
        }
        float s = 0.f;
        #pragma unroll
        for (int mt = 0; mt < 4; ++mt) {
            const f32x4 bv = *(const f32x4*)&b4_s[64 * c + 16 * mt + 4 * g];
            #pragma unroll
            for (int q = 0; q < 4; ++q)
                s += (acc[mt][q] + bv[q]) * xmr[mt][q];
        }
        s += __shfl_xor(s, 16);
        s += __shfl_xor(s, 32);
        if (g == 0) hid_s[r_local * 68 + c] = s;
    }
    __syncthreads();

    // ---------------- chunk 64: inp_b (wave handles m-tile = cw) + ReLU
    {
        const f16* Ab = W4h + (size_t)4096 * 128;
        f32x4 acc = zero;
        #pragma unroll
        for (int kk = 0; kk < 4; ++kk) {
            const f16x8 av = *(const f16x8*)&Ab[(16 * cw + lr) * 128 + 32 * kk + 8 * g];
            acc = __builtin_amdgcn_mfma_f32_16x16x32_f16(av, bfrag[kk], acc, 0, 0, 0);
        }
        const int hb = 16 * cw + 4 * g;
        f32x4 hv = *(const f32x4*)&hid_s[r_local * 68 + hb];
        const f32x4 bv = *(const f32x4*)&b4_s[4096 + hb];
        #pragma unroll
        for (int q = 0; q < 4; ++q)
            hv[q] = fmaxf(hv[q] + acc[q] + bv[q], 0.f);
        *(f32x4*)&hid_s[r_local * 68 + hb] = hv;
    }
    __syncthreads();

    // hid registers for the out-phase epilogue: hid[r_local][16mt+4g .. +4]
    f32x4 hidr[4];
    #pragma unroll
    for (int mt = 0; mt < 4; ++mt)
        hidr[mt] = *(const f32x4*)&hid_s[r_local * 68 + 16 * mt + 4 * g];

    // ---------------- out_w chunks: c in {65+cw, 69+cw, 73+cw} ∩ [65,74]
    for (int c = 65 + cw; c <= 74; c += 4) {
        const f16* Ab = W4h + (size_t)(64 * c) * 128;
        f16x8 a[4][4];
        #pragma unroll
        for (int mt = 0; mt < 4; ++mt)
            a[0][mt] = *(const f16x8*)&Ab[(16 * mt + lr) * 128 + 8 * g];
        #pragma unroll
        for (int mt = 0; mt < 4; ++mt)
            a[1][mt] = *(const f16x8*)&Ab[(16 * mt + lr) * 128 + 32 + 8 * g];
        f32x4 acc[4] = {zero, zero, zero, zero};
        #pragma unroll
        for (int kk = 0; kk < 4; ++kk) {
            if (kk < 2) {
                #pragma unroll
                for (int mt = 0; mt < 4; ++mt)
                    a[kk + 2][mt] = *(const f16x8*)&Ab[(16 * mt + lr) * 128 + 32 * (kk + 2) + 8 * g];
            }
            #pragma unroll
            for (int mt = 0; mt < 4; ++mt)
                acc[mt] = __builtin_amdgcn_mfma_f32_16x16x32_f16(a[kk][mt], bfrag[kk], acc[mt], 0, 0, 0);
        }
        float s = 0.f;
        #pragma unroll
        for (int mt = 0; mt < 4; ++mt) {
            const f32x4 bv = *(const f32x4*)&b4_s[64 * c + 16 * mt + 4 * g];
            #pragma unroll
            for (int q = 0; q < 4; ++q)
                s += (acc[mt][q] + bv[q]) * hidr[mt][q];
        }
        s += __shfl_xor(s, 16);
        s += __shfl_xor(s, 32);
        if (g == 0) res_s[r_local * 12 + (c - 65)] = s;
    }
    __syncthreads();

    // ---------------- chunk 75: out_b (rows 4800..4809; 4810+ zero-padded)
    if (cw == 3) {
        const f16* Ab = W4h + (size_t)4800 * 128;
        f32x4 acc = zero;
        #pragma unroll
        for (int kk = 0; kk < 4; ++kk) {
            const f16x8 av = *(const f16x8*)&Ab[lr * 128 + 32 * kk + 8 * g];
            acc = __builtin_amdgcn_mfma_f32_16x16x32_f16(av, bfrag[kk], acc, 0, 0, 0);
        }
        #pragma unroll
        for (int q = 0; q < 4; ++q) {
            const int o = 4 * g + q;
            if (o < 10)
                res_s[r_local * 12 + o] += acc[q] + b4_s[4800 + o];
        }
    }
    __syncthreads();

    for (int e = t; e < 320; e += 512)
        out[(size_t)row0 * 10 + e] = res_s[(e / 10) * 12 + (e % 10)];
}

// ---------------------------------------------------------------- launcher
extern "C" void kernel_launch(void* const* d_in, const int* in_sizes, int n_in,
                              void* d_out, int out_size, void* d_ws, size_t ws_size,
                              hipStream_t stream)
{
    const float* data = (const float*)d_in[0];
    const int*   midx = (const int*)d_in[1];
    const float* W1   = (const float*)d_in[2];
    const float* b1   = (const float*)d_in[3];
    const float* W2   = (const float*)d_in[4];
    const float* b2   = (const float*)d_in[5];
    const float* W3   = (const float*)d_in[6];
    const float* b3   = (const float*)d_in[7];
    const float* W4   = (const float*)d_in[8];
    const float* b4   = (const float*)d_in[9];
    float* out = (float*)d_out;

    float* W1T   = (float*)d_ws;                      // 262144 f32
    float* xm_ws = W1T + 4096 * 64;                   // 1048576 f32
    f16*   h3h   = (f16*)(xm_ws + (size_t)16384 * 64);// 2097152 f16
    f16*   W4h   = h3h + (size_t)16384 * 128;         // 622592 f16

    k_prep <<<512, 256, 0, stream>>>(W1, W4, W1T, W4h);
    k_mlp  <<<512, 256, 0, stream>>>(data, midx, W1T, b1, W2, b2, W3, b3, xm_ws, h3h);
    k_hyper<<<512, 512, 0, stream>>>(xm_ws, h3h, W4h, b4, out);
}

// Round 3
// 186.269 us; speedup vs baseline: 3.4657x; 1.5843x over previous
//
#include <hip/hip_runtime.h>

// INP=4096 MSK=64 HID=64 OUT=10  L1=64 L2=256 L3=128  B=16384  WVEC=4810
// Pipeline:
//   k_prep   : W1^T (f32), W2/W3/W4 -> f16
//   k_gather : xm gather + layer1 dedup gather-sum (latency-optimized, 8192 waves)
//   k_l23    : layers 2+3 as f16 MFMA, h2 in XOR-swizzled LDS
//   k_hyper  : step-5 GEMM (f16 MFMA, A from L2) + fused per-sample einsums

typedef _Float16 f16;
typedef _Float16 f16x8 __attribute__((ext_vector_type(8)));
typedef _Float16 f16x4 __attribute__((ext_vector_type(4)));
typedef float    f32x4 __attribute__((ext_vector_type(4)));

#define NPAD 4864   // 4810 W4 rows padded to 76*64

// ---------------------------------------------------------------- prep
__global__ __launch_bounds__(256) void k_prep(
    const float* __restrict__ W1, const float* __restrict__ W2,
    const float* __restrict__ W3, const float* __restrict__ W4,
    float* __restrict__ W1T, f16* __restrict__ W2h,
    f16* __restrict__ W3h, f16* __restrict__ W4h)
{
    const int tid = blockIdx.x * 256 + threadIdx.x;
    const int stride = gridDim.x * 256;
    for (int e = tid; e < 4096 * 64; e += stride) {
        int j = e >> 6, i = e & 63;
        W1T[e] = W1[(size_t)i * 4096 + j];
    }
    for (int e = tid; e < NPAD * 128; e += stride) {
        int n = e >> 7;
        W4h[e] = (n < 4810) ? (f16)W4[e] : (f16)0.f;
    }
    for (int e = tid; e < 256 * 64; e += stride)  W2h[e] = (f16)W2[e];
    for (int e = tid; e < 128 * 256; e += stride) W3h[e] = (f16)W3[e];
}

// ------------------------------------------- gather + layer 1 (dedup sum)
// 2048 blocks x 4 waves, 2 rows/wave -> 8192 waves, tiny LDS/VGPR.
__global__ __launch_bounds__(256) void k_gather(
    const float* __restrict__ data, const int* __restrict__ midx,
    const float* __restrict__ W1T, const float* __restrict__ b1,
    float* __restrict__ xm_out, f16* __restrict__ h1h)
{
    __shared__ int idx_s[8 * 64];
    const int t = threadIdx.x;
    const int row0 = blockIdx.x * 8;

    for (int e = t; e < 512; e += 256)
        idx_s[e] = midx[(size_t)row0 * 64 + e];
    __syncthreads();

    const int wv = t >> 6, lane = t & 63;
    const int rA = 2 * wv, rB = rA + 1;

    // xm gather (1 random 4B load per row per lane)
    const int giA = idx_s[rA * 64 + lane];
    const int giB = idx_s[rB * 64 + lane];
    xm_out[(size_t)(row0 + rA) * 64 + lane] = data[(size_t)(row0 + rA) * 4096 + giA];
    xm_out[(size_t)(row0 + rB) * 64 + lane] = data[(size_t)(row0 + rB) * 4096 + giB];

    // layer 1: deduped gather-sum of W1T rows (sorted -> adjacent-equal skip)
    const float b1v = b1[lane];
    float aA = b1v, aB = b1v;
    int pA = -1, pB = -1;
    #pragma unroll 8
    for (int i = 0; i < 64; ++i) {
        const int cA = idx_s[rA * 64 + i];
        const int cB = idx_s[rB * 64 + i];
        const float wA = W1T[cA * 64 + lane];
        const float wB = W1T[cB * 64 + lane];
        aA += (cA != pA) ? wA : 0.f;  pA = cA;
        aB += (cB != pB) ? wB : 0.f;  pB = cB;
    }
    h1h[(size_t)(row0 + rA) * 64 + lane] = (f16)fmaxf(aA, 0.f);
    h1h[(size_t)(row0 + rB) * 64 + lane] = (f16)fmaxf(aB, 0.f);
}

// ------------------------------------------- layers 2+3 via f16 MFMA
// 512 blocks x 256 thr (4 waves), 32 samples/block.
// L2: wave w owns n in [64w,64w+64): tiles mt(n)=0..3 x rt(sample)=0..1, K=64.
// h2 -> LDS f16 [s][256] with byte-XOR swizzle ^((s&7)<<4) (bank spread).
// L3: wave w owns n' in [32w,32w+32): mt2=0..1 x rt=0..1, K=256.
__global__ __launch_bounds__(256) void k_l23(
    const f16* __restrict__ h1h, const f16* __restrict__ W2h,
    const float* __restrict__ b2, const f16* __restrict__ W3h,
    const float* __restrict__ b3, f16* __restrict__ h3h)
{
    __shared__ __align__(16) f16 h2_s[32 * 256];   // 16 KB, swizzled

    const int t = threadIdx.x, w = t >> 6, lane = t & 63;
    const int lr = lane & 15, g = lane >> 4;
    const int row0 = blockIdx.x * 32;
    const f32x4 zero = {0.f, 0.f, 0.f, 0.f};
    char* h2b = (char*)h2_s;

    // ---- layer 2
    f16x8 a2[4][2], bf[2][2];
    #pragma unroll
    for (int mt = 0; mt < 4; ++mt)
        #pragma unroll
        for (int kk = 0; kk < 2; ++kk)
            a2[mt][kk] = *(const f16x8*)&W2h[(64 * w + 16 * mt + lr) * 64 + 32 * kk + 8 * g];
    #pragma unroll
    for (int rt = 0; rt < 2; ++rt)
        #pragma unroll
        for (int kk = 0; kk < 2; ++kk)
            bf[rt][kk] = *(const f16x8*)&h1h[((size_t)row0 + 16 * rt + lr) * 64 + 32 * kk + 8 * g];

    f32x4 acc[4][2];
    #pragma unroll
    for (int mt = 0; mt < 4; ++mt)
        #pragma unroll
        for (int rt = 0; rt < 2; ++rt) acc[mt][rt] = zero;
    #pragma unroll
    for (int kk = 0; kk < 2; ++kk)
        #pragma unroll
        for (int mt = 0; mt < 4; ++mt)
            #pragma unroll
            for (int rt = 0; rt < 2; ++rt)
                acc[mt][rt] = __builtin_amdgcn_mfma_f32_16x16x32_f16(a2[mt][kk], bf[rt][kk], acc[mt][rt], 0, 0, 0);

    #pragma unroll
    for (int mt = 0; mt < 4; ++mt) {
        const f32x4 bv = *(const f32x4*)&b2[64 * w + 16 * mt + 4 * g];
        #pragma unroll
        for (int rt = 0; rt < 2; ++rt) {
            const int s = 16 * rt + lr;
            f16x4 hv;
            #pragma unroll
            for (int q = 0; q < 4; ++q)
                hv[q] = (f16)fmaxf(acc[mt][rt][q] + bv[q], 0.f);
            const int byte = (s * 512 + (64 * w + 16 * mt + 4 * g) * 2) ^ ((s & 7) << 4);
            *(f16x4*)(h2b + byte) = hv;
        }
    }
    __syncthreads();

    // ---- layer 3
    f32x4 acc3[2][2];
    #pragma unroll
    for (int mt = 0; mt < 2; ++mt)
        #pragma unroll
        for (int rt = 0; rt < 2; ++rt) acc3[mt][rt] = zero;
    #pragma unroll 2
    for (int kk = 0; kk < 8; ++kk) {
        f16x8 a3[2], b3f[2];
        #pragma unroll
        for (int mt = 0; mt < 2; ++mt)
            a3[mt] = *(const f16x8*)&W3h[(32 * w + 16 * mt + lr) * 256 + 32 * kk + 8 * g];
        #pragma unroll
        for (int rt = 0; rt < 2; ++rt) {
            const int s = 16 * rt + lr;
            const int byte = (s * 512 + (32 * kk + 8 * g) * 2) ^ ((s & 7) << 4);
            b3f[rt] = *(const f16x8*)(h2b + byte);
        }
        #pragma unroll
        for (int mt = 0; mt < 2; ++mt)
            #pragma unroll
            for (int rt = 0; rt < 2; ++rt)
                acc3[mt][rt] = __builtin_amdgcn_mfma_f32_16x16x32_f16(a3[mt], b3f[rt], acc3[mt][rt], 0, 0, 0);
    }
    #pragma unroll
    for (int mt = 0; mt < 2; ++mt) {
        const f32x4 bv = *(const f32x4*)&b3[32 * w + 16 * mt + 4 * g];
        #pragma unroll
        for (int rt = 0; rt < 2; ++rt) {
            const int s = 16 * rt + lr;
            f16x4 hv;
            #pragma unroll
            for (int q = 0; q < 4; ++q)
                hv[q] = (f16)fmaxf(acc3[mt][rt][q] + bv[q], 0.f);
            *(f16x4*)&h3h[((size_t)row0 + s) * 128 + 32 * w + 16 * mt + 4 * g] = hv;
        }
    }
}

// -------------------------- steps 5+8+9: MFMA W4 GEMM + register epilogues
__global__ __launch_bounds__(512, 4) void k_hyper(
    const float* __restrict__ xmg, const f16* __restrict__ h3h,
    const f16* __restrict__ W4h, const float* __restrict__ b4,
    float* __restrict__ out)
{
    __shared__ __align__(16) float b4_s[NPAD];
    __shared__ __align__(16) float hid_s[32 * 68];
    __shared__ __align__(16) float res_s[32 * 12];

    const int t = threadIdx.x;
    const int w = t >> 6;
    const int lane = t & 63;
    const int rw = w >> 2;          // sample group
    const int cw = w & 3;           // chunk group
    const int lr = lane & 15;
    const int g  = lane >> 4;       // k-group / m-subgroup
    const int r_local = lr + 16 * rw;
    const int row0 = blockIdx.x * 32;
    const size_t grow = (size_t)(row0 + r_local);

    for (int i = t; i < NPAD; i += 512)
        b4_s[i] = (i < 4810) ? b4[i] : 0.f;

    // B-fragments (h3, chunk-invariant): lane holds h3[r_local][32kk+8g .. +8]
    f16x8 bfrag[4];
    #pragma unroll
    for (int kk = 0; kk < 4; ++kk)
        bfrag[kk] = *(const f16x8*)&h3h[grow * 128 + 32 * kk + 8 * g];

    // xm registers: xm[r_local][16mt+4g .. +4]
    f32x4 xmr[4];
    #pragma unroll
    for (int mt = 0; mt < 4; ++mt)
        xmr[mt] = *(const f32x4*)&xmg[grow * 64 + 16 * mt + 4 * g];

    __syncthreads();   // b4_s ready

    const f32x4 zero = {0.f, 0.f, 0.f, 0.f};

    // ---------------- inp_w chunks: c = cw + 4j -> hid_s[r][c]
    for (int j = 0; j < 16; ++j) {
        const int c = cw + 4 * j;
        const f16* Ab = W4h + (size_t)(64 * c) * 128;
        f16x8 a[4][4];                       // [kk][mt]
        #pragma unroll
        for (int mt = 0; mt < 4; ++mt)
            a[0][mt] = *(const f16x8*)&Ab[(16 * mt + lr) * 128 + 8 * g];
        #pragma unroll
        for (int mt = 0; mt < 4; ++mt)
            a[1][mt] = *(const f16x8*)&Ab[(16 * mt + lr) * 128 + 32 + 8 * g];
        f32x4 acc[4] = {zero, zero, zero, zero};
        #pragma unroll
        for (int kk = 0; kk < 4; ++kk) {
            if (kk < 2) {
                #pragma unroll
                for (int mt = 0; mt < 4; ++mt)
                    a[kk + 2][mt] = *(const f16x8*)&Ab[(16 * mt + lr) * 128 + 32 * (kk + 2) + 8 * g];
            }
            #pragma unroll
            for (int mt = 0; mt < 4; ++mt)
                acc[mt] = __builtin_amdgcn_mfma_f32_16x16x32_f16(a[kk][mt], bfrag[kk], acc[mt], 0, 0, 0);
        }
        float s = 0.f;
        #pragma unroll
        for (int mt = 0; mt < 4; ++mt) {
            const f32x4 bv = *(const f32x4*)&b4_s[64 * c + 16 * mt + 4 * g];
            #pragma unroll
            for (int q = 0; q < 4; ++q)
                s += (acc[mt][q] + bv[q]) * xmr[mt][q];
        }
        s += __shfl_xor(s, 16);
        s += __shfl_xor(s, 32);
        if (g == 0) hid_s[r_local * 68 + c] = s;
    }
    __syncthreads();

    // ---------------- chunk 64: inp_b (wave handles m-tile = cw) + ReLU
    {
        const f16* Ab = W4h + (size_t)4096 * 128;
        f32x4 acc = zero;
        #pragma unroll
        for (int kk = 0; kk < 4; ++kk) {
            const f16x8 av = *(const f16x8*)&Ab[(16 * cw + lr) * 128 + 32 * kk + 8 * g];
            acc = __builtin_amdgcn_mfma_f32_16x16x32_f16(av, bfrag[kk], acc, 0, 0, 0);
        }
        const int hb = 16 * cw + 4 * g;
        f32x4 hv = *(const f32x4*)&hid_s[r_local * 68 + hb];
        const f32x4 bv = *(const f32x4*)&b4_s[4096 + hb];
        #pragma unroll
        for (int q = 0; q < 4; ++q)
            hv[q] = fmaxf(hv[q] + acc[q] + bv[q], 0.f);
        *(f32x4*)&hid_s[r_local * 68 + hb] = hv;
    }
    __syncthreads();

    // hid registers for the out-phase epilogue: hid[r_local][16mt+4g .. +4]
    f32x4 hidr[4];
    #pragma unroll
    for (int mt = 0; mt < 4; ++mt)
        hidr[mt] = *(const f32x4*)&hid_s[r_local * 68 + 16 * mt + 4 * g];

    // ---------------- out_w chunks: c in {65+cw, 69+cw, 73+cw} ∩ [65,74]
    for (int c = 65 + cw; c <= 74; c += 4) {
        const f16* Ab = W4h + (size_t)(64 * c) * 128;
        f16x8 a[4][4];
        #pragma unroll
        for (int mt = 0; mt < 4; ++mt)
            a[0][mt] = *(const f16x8*)&Ab[(16 * mt + lr) * 128 + 8 * g];
        #pragma unroll
        for (int mt = 0; mt < 4; ++mt)
            a[1][mt] = *(const f16x8*)&Ab[(16 * mt + lr) * 128 + 32 + 8 * g];
        f32x4 acc[4] = {zero, zero, zero, zero};
        #pragma unroll
        for (int kk = 0; kk < 4; ++kk) {
            if (kk < 2) {
                #pragma unroll
                for (int mt = 0; mt < 4; ++mt)
                    a[kk + 2][mt] = *(const f16x8*)&Ab[(16 * mt + lr) * 128 + 32 * (kk + 2) + 8 * g];
            }
            #pragma unroll
            for (int mt = 0; mt < 4; ++mt)
                acc[mt] = __builtin_amdgcn_mfma_f32_16x16x32_f16(a[kk][mt], bfrag[kk], acc[mt], 0, 0, 0);
        }
        float s = 0.f;
        #pragma unroll
        for (int mt = 0; mt < 4; ++mt) {
            const f32x4 bv = *(const f32x4*)&b4_s[64 * c + 16 * mt + 4 * g];
            #pragma unroll
            for (int q = 0; q < 4; ++q)
                s += (acc[mt][q] + bv[q]) * hidr[mt][q];
        }
        s += __shfl_xor(s, 16);
        s += __shfl_xor(s, 32);
        if (g == 0) res_s[r_local * 12 + (c - 65)] = s;
    }
    __syncthreads();

    // ---------------- chunk 75: out_b (rows 4800..4809; 4810+ zero-padded)
    if (cw == 3) {
        const f16* Ab = W4h + (size_t)4800 * 128;
        f32x4 acc = zero;
        #pragma unroll
        for (int kk = 0; kk < 4; ++kk) {
            const f16x8 av = *(const f16x8*)&Ab[lr * 128 + 32 * kk + 8 * g];
            acc = __builtin_amdgcn_mfma_f32_16x16x32_f16(av, bfrag[kk], acc, 0, 0, 0);
        }
        #pragma unroll
        for (int q = 0; q < 4; ++q) {
            const int o = 4 * g + q;
            if (o < 10)
                res_s[r_local * 12 + o] += acc[q] + b4_s[4800 + o];
        }
    }
    __syncthreads();

    for (int e = t; e < 320; e += 512)
        out[(size_t)row0 * 10 + e] = res_s[(e / 10) * 12 + (e % 10)];
}

// ---------------------------------------------------------------- launcher
extern "C" void kernel_launch(void* const* d_in, const int* in_sizes, int n_in,
                              void* d_out, int out_size, void* d_ws, size_t ws_size,
                              hipStream_t stream)
{
    const float* data = (const float*)d_in[0];
    const int*   midx = (const int*)d_in[1];
    const float* W1   = (const float*)d_in[2];
    const float* b1   = (const float*)d_in[3];
    const float* W2   = (const float*)d_in[4];
    const float* b2   = (const float*)d_in[5];
    const float* W3   = (const float*)d_in[6];
    const float* b3   = (const float*)d_in[7];
    const float* W4   = (const float*)d_in[8];
    const float* b4   = (const float*)d_in[9];
    float* out = (float*)d_out;

    float* W1T   = (float*)d_ws;                        // 262144 f32
    float* xm_ws = W1T + 4096 * 64;                     // 1048576 f32
    f16*   h1h   = (f16*)(xm_ws + (size_t)16384 * 64);  // 1048576 f16
    f16*   h3h   = h1h + (size_t)16384 * 64;            // 2097152 f16
    f16*   W4h   = h3h + (size_t)16384 * 128;           // 622592 f16
    f16*   W2h   = W4h + (size_t)NPAD * 128;            // 16384 f16
    f16*   W3h   = W2h + 256 * 64;                      // 32768 f16

    k_prep  <<<512, 256, 0, stream>>>(W1, W2, W3, W4, W1T, W2h, W3h, W4h);
    k_gather<<<2048, 256, 0, stream>>>(data, midx, W1T, b1, xm_ws, h1h);
    k_l23   <<<512, 256, 0, stream>>>(h1h, W2h, b2, W3h, b3, h3h);
    k_hyper <<<512, 512, 0, stream>>>(xm_ws, h3h, W4h, b4, out);
}

// Round 4
// 115.807 us; speedup vs baseline: 5.5743x; 1.6084x over previous
//
#include <hip/hip_runtime.h>

// INP=4096 MSK=64 HID=64 OUT=10  L1=64 L2=256 L3=128  B=16384  WVEC=4810
// Pipeline:
//   k_prep   : W1^T (f32), W2/W3/W4 -> f16
//   k_gather : xm gather + layer1 dedup gather-sum (8192 waves, latency-bound)
//   k_hyper  : layers 2+3 (f16 MFMA, LDS h2/h3) + step-5 GEMM (A from L2,
//              2x reuse across sample halves) + fused per-sample einsums

typedef _Float16 f16;
typedef _Float16 f16x8 __attribute__((ext_vector_type(8)));
typedef _Float16 f16x4 __attribute__((ext_vector_type(4)));
typedef float    f32x4 __attribute__((ext_vector_type(4)));

#define NPAD 4864   // 4810 W4 rows padded to 76*64

// ---------------------------------------------------------------- prep
__global__ __launch_bounds__(256) void k_prep(
    const float* __restrict__ W1, const float* __restrict__ W2,
    const float* __restrict__ W3, const float* __restrict__ W4,
    float* __restrict__ W1T, f16* __restrict__ W2h,
    f16* __restrict__ W3h, f16* __restrict__ W4h)
{
    const int tid = blockIdx.x * 256 + threadIdx.x;
    const int stride = gridDim.x * 256;
    for (int e = tid; e < 4096 * 64; e += stride) {
        int j = e >> 6, i = e & 63;
        W1T[e] = W1[(size_t)i * 4096 + j];
    }
    for (int e = tid; e < NPAD * 128; e += stride) {
        int n = e >> 7;
        W4h[e] = (n < 4810) ? (f16)W4[e] : (f16)0.f;
    }
    for (int e = tid; e < 256 * 64; e += stride)  W2h[e] = (f16)W2[e];
    for (int e = tid; e < 128 * 256; e += stride) W3h[e] = (f16)W3[e];
}

// ------------------------------------------- gather + layer 1 (dedup sum)
__global__ __launch_bounds__(256) void k_gather(
    const float* __restrict__ data, const int* __restrict__ midx,
    const float* __restrict__ W1T, const float* __restrict__ b1,
    float* __restrict__ xm_out, f16* __restrict__ h1h)
{
    __shared__ int idx_s[8 * 64];
    const int t = threadIdx.x;
    const int row0 = blockIdx.x * 8;

    for (int e = t; e < 512; e += 256)
        idx_s[e] = midx[(size_t)row0 * 64 + e];
    __syncthreads();

    const int wv = t >> 6, lane = t & 63;
    const int rA = 2 * wv, rB = rA + 1;

    const int giA = idx_s[rA * 64 + lane];
    const int giB = idx_s[rB * 64 + lane];
    xm_out[(size_t)(row0 + rA) * 64 + lane] = data[(size_t)(row0 + rA) * 4096 + giA];
    xm_out[(size_t)(row0 + rB) * 64 + lane] = data[(size_t)(row0 + rB) * 4096 + giB];

    const float b1v = b1[lane];
    float aA = b1v, aB = b1v;
    int pA = -1, pB = -1;
    #pragma unroll 8
    for (int i = 0; i < 64; ++i) {
        const int cA = idx_s[rA * 64 + i];
        const int cB = idx_s[rB * 64 + i];
        const float wA = W1T[cA * 64 + lane];
        const float wB = W1T[cB * 64 + lane];
        aA += (cA != pA) ? wA : 0.f;  pA = cA;
        aB += (cB != pB) ? wB : 0.f;  pB = cB;
    }
    h1h[(size_t)(row0 + rA) * 64 + lane] = (f16)fmaxf(aA, 0.f);
    h1h[(size_t)(row0 + rB) * 64 + lane] = (f16)fmaxf(aB, 0.f);
}

// ------------------- fused: layers 2+3 + W4 GEMM + per-sample epilogues
// 256 blocks x 512 thr (8 waves), 64 samples/block (grid == CU count).
// Wave (rs = w>>2, cw = w&3): sample half rs (2 bfrag sets u=0,1 of 16),
// chunk group cw. A-fragments loaded once, used for both sample sets.
__global__ __launch_bounds__(512, 2) void k_hyper(
    const float* __restrict__ xmg, const f16* __restrict__ h1h,
    const f16* __restrict__ W2h, const float* __restrict__ b2,
    const f16* __restrict__ W3h, const float* __restrict__ b3,
    const f16* __restrict__ W4h, const float* __restrict__ b4,
    float* __restrict__ out)
{
    __shared__ __align__(16) float b4_s[NPAD];      // 19.5 KB
    __shared__ __align__(16) f16 h2_s[64 * 256];    // 32 KB (swizzled)
    __shared__ __align__(16) f16 h3_s[64 * 128];    // 16 KB (swizzled)
    __shared__ __align__(16) float hid_s[64 * 68];  // 17.4 KB
    __shared__ __align__(16) float res_s[64 * 12];  // 3 KB

    const int t = threadIdx.x, w = t >> 6, lane = t & 63;
    const int lr = lane & 15, g = lane >> 4;
    const int rs = w >> 2, cw = w & 3;
    const int row0 = blockIdx.x * 64;
    const f32x4 zero = {0.f, 0.f, 0.f, 0.f};
    char* h2b = (char*)h2_s;
    char* h3b = (char*)h3_s;

    for (int i = t; i < NPAD; i += 512)
        b4_s[i] = (i < 4810) ? b4[i] : 0.f;

    // ---------------- layer 2: wave w owns n in [32w,32w+32), K=64
    {
        f16x8 a2[2][2], bh[4][2];
        #pragma unroll
        for (int mt = 0; mt < 2; ++mt)
            #pragma unroll
            for (int kk = 0; kk < 2; ++kk)
                a2[mt][kk] = *(const f16x8*)&W2h[(32 * w + 16 * mt + lr) * 64 + 32 * kk + 8 * g];
        #pragma unroll
        for (int rt = 0; rt < 4; ++rt)
            #pragma unroll
            for (int kk = 0; kk < 2; ++kk)
                bh[rt][kk] = *(const f16x8*)&h1h[((size_t)row0 + 16 * rt + lr) * 64 + 32 * kk + 8 * g];

        f32x4 acc2[2][4];
        #pragma unroll
        for (int mt = 0; mt < 2; ++mt)
            #pragma unroll
            for (int rt = 0; rt < 4; ++rt)
                acc2[mt][rt] = __builtin_amdgcn_mfma_f32_16x16x32_f16(a2[mt][0], bh[rt][0], zero, 0, 0, 0);
        #pragma unroll
        for (int mt = 0; mt < 2; ++mt)
            #pragma unroll
            for (int rt = 0; rt < 4; ++rt)
                acc2[mt][rt] = __builtin_amdgcn_mfma_f32_16x16x32_f16(a2[mt][1], bh[rt][1], acc2[mt][rt], 0, 0, 0);

        #pragma unroll
        for (int mt = 0; mt < 2; ++mt) {
            const f32x4 bv = *(const f32x4*)&b2[32 * w + 16 * mt + 4 * g];
            #pragma unroll
            for (int rt = 0; rt < 4; ++rt) {
                const int s = 16 * rt + lr;
                f16x4 hv;
                #pragma unroll
                for (int q = 0; q < 4; ++q)
                    hv[q] = (f16)fmaxf(acc2[mt][rt][q] + bv[q], 0.f);
                const int byte = (s * 512 + (32 * w + 16 * mt + 4 * g) * 2) ^ ((s & 7) << 4);
                *(f16x4*)(h2b + byte) = hv;
            }
        }
    }
    __syncthreads();

    // ---------------- layer 3: wave w owns n in [16w,16w+16), K=256
    {
        f32x4 acc3[4] = {zero, zero, zero, zero};
        #pragma unroll 2
        for (int kk = 0; kk < 8; ++kk) {
            const f16x8 a3 = *(const f16x8*)&W3h[(16 * w + lr) * 256 + 32 * kk + 8 * g];
            #pragma unroll
            for (int rt = 0; rt < 4; ++rt) {
                const int s = 16 * rt + lr;
                const int byte = (s * 512 + (32 * kk + 8 * g) * 2) ^ ((s & 7) << 4);
                const f16x8 bb = *(const f16x8*)(h2b + byte);
                acc3[rt] = __builtin_amdgcn_mfma_f32_16x16x32_f16(a3, bb, acc3[rt], 0, 0, 0);
            }
        }
        const f32x4 bv3 = *(const f32x4*)&b3[16 * w + 4 * g];
        #pragma unroll
        for (int rt = 0; rt < 4; ++rt) {
            const int s = 16 * rt + lr;
            f16x4 hv;
            #pragma unroll
            for (int q = 0; q < 4; ++q)
                hv[q] = (f16)fmaxf(acc3[rt][q] + bv3[q], 0.f);
            const int byte = (s * 256 + (16 * w + 4 * g) * 2) ^ ((s & 7) << 4);
            *(f16x4*)(h3b + byte) = hv;
        }
    }
    __syncthreads();

    // B-fragments from LDS h3 (chunk-invariant), 2 sample sets per wave
    f16x8 bfrag[2][4];
    #pragma unroll
    for (int u = 0; u < 2; ++u)
        #pragma unroll
        for (int kk = 0; kk < 4; ++kk) {
            const int s = 32 * rs + 16 * u + lr;
            const int byte = (s * 256 + (32 * kk + 8 * g) * 2) ^ ((s & 7) << 4);
            bfrag[u][kk] = *(const f16x8*)(h3b + byte);
        }

    // xm registers: xm[sample][16mt+4g .. +4]
    f32x4 xmr[2][4];
    #pragma unroll
    for (int u = 0; u < 2; ++u)
        #pragma unroll
        for (int mt = 0; mt < 4; ++mt)
            xmr[u][mt] = *(const f32x4*)&xmg[((size_t)row0 + 32 * rs + 16 * u + lr) * 64 + 16 * mt + 4 * g];

    // ---------------- inp_w chunks: c = cw + 4j -> hid_s[sample][c]
    for (int j = 0; j < 16; ++j) {
        const int c = cw + 4 * j;
        const f16* Ab = W4h + (size_t)(64 * c) * 128;
        f16x8 a[4][4];                       // [kk][mt]
        #pragma unroll
        for (int mt = 0; mt < 4; ++mt)
            a[0][mt] = *(const f16x8*)&Ab[(16 * mt + lr) * 128 + 8 * g];
        #pragma unroll
        for (int mt = 0; mt < 4; ++mt)
            a[1][mt] = *(const f16x8*)&Ab[(16 * mt + lr) * 128 + 32 + 8 * g];

        f32x4 acc[4][2];
        #pragma unroll
        for (int kk = 0; kk < 4; ++kk) {
            if (kk < 2) {
                #pragma unroll
                for (int mt = 0; mt < 4; ++mt)
                    a[kk + 2][mt] = *(const f16x8*)&Ab[(16 * mt + lr) * 128 + 32 * (kk + 2) + 8 * g];
            }
            #pragma unroll
            for (int mt = 0; mt < 4; ++mt)
                #pragma unroll
                for (int u = 0; u < 2; ++u)
                    acc[mt][u] = (kk == 0)
                        ? __builtin_amdgcn_mfma_f32_16x16x32_f16(a[0][mt], bfrag[u][0], zero, 0, 0, 0)
                        : __builtin_amdgcn_mfma_f32_16x16x32_f16(a[kk][mt], bfrag[u][kk], acc[mt][u], 0, 0, 0);
        }

        f32x4 bv[4];
        #pragma unroll
        for (int mt = 0; mt < 4; ++mt)
            bv[mt] = *(const f32x4*)&b4_s[64 * c + 16 * mt + 4 * g];

        #pragma unroll
        for (int u = 0; u < 2; ++u) {
            float s = 0.f;
            #pragma unroll
            for (int mt = 0; mt < 4; ++mt)
                #pragma unroll
                for (int q = 0; q < 4; ++q)
                    s += (acc[mt][u][q] + bv[mt][q]) * xmr[u][mt][q];
            s += __shfl_xor(s, 16);
            s += __shfl_xor(s, 32);
            if (g == 0) hid_s[(32 * rs + 16 * u + lr) * 68 + c] = s;
        }
    }
    __syncthreads();

    // ---------------- chunk 64: inp_b (wave handles h-tile = cw) + ReLU
    {
        const f16* Ab = W4h + (size_t)4096 * 128;
        f16x8 a[4];
        #pragma unroll
        for (int kk = 0; kk < 4; ++kk)
            a[kk] = *(const f16x8*)&Ab[(16 * cw + lr) * 128 + 32 * kk + 8 * g];
        #pragma unroll
        for (int u = 0; u < 2; ++u) {
            f32x4 acc = zero;
            #pragma unroll
            for (int kk = 0; kk < 4; ++kk)
                acc = __builtin_amdgcn_mfma_f32_16x16x32_f16(a[kk], bfrag[u][kk], acc, 0, 0, 0);
            const int s = 32 * rs + 16 * u + lr;
            const int hb = 16 * cw + 4 * g;
            f32x4 hv = *(const f32x4*)&hid_s[s * 68 + hb];
            const f32x4 bv = *(const f32x4*)&b4_s[4096 + hb];
            #pragma unroll
            for (int q = 0; q < 4; ++q)
                hv[q] = fmaxf(hv[q] + acc[q] + bv[q], 0.f);
            *(f32x4*)&hid_s[s * 68 + hb] = hv;
        }
    }
    __syncthreads();

    // hid registers for the out-phase epilogue
    f32x4 hidr[2][4];
    #pragma unroll
    for (int u = 0; u < 2; ++u)
        #pragma unroll
        for (int mt = 0; mt < 4; ++mt)
            hidr[u][mt] = *(const f32x4*)&hid_s[(32 * rs + 16 * u + lr) * 68 + 16 * mt + 4 * g];

    // ---------------- out_w chunks: c in {65+cw, 69+cw, 73+cw} ∩ [65,74]
    for (int c = 65 + cw; c <= 74; c += 4) {
        const f16* Ab = W4h + (size_t)(64 * c) * 128;
        f16x8 a[4][4];
        #pragma unroll
        for (int mt = 0; mt < 4; ++mt)
            a[0][mt] = *(const f16x8*)&Ab[(16 * mt + lr) * 128 + 8 * g];
        #pragma unroll
        for (int mt = 0; mt < 4; ++mt)
            a[1][mt] = *(const f16x8*)&Ab[(16 * mt + lr) * 128 + 32 + 8 * g];

        f32x4 acc[4][2];
        #pragma unroll
        for (int kk = 0; kk < 4; ++kk) {
            if (kk < 2) {
                #pragma unroll
                for (int mt = 0; mt < 4; ++mt)
                    a[kk + 2][mt] = *(const f16x8*)&Ab[(16 * mt + lr) * 128 + 32 * (kk + 2) + 8 * g];
            }
            #pragma unroll
            for (int mt = 0; mt < 4; ++mt)
                #pragma unroll
                for (int u = 0; u < 2; ++u)
                    acc[mt][u] = (kk == 0)
                        ? __builtin_amdgcn_mfma_f32_16x16x32_f16(a[0][mt], bfrag[u][0], zero, 0, 0, 0)
                        : __builtin_amdgcn_mfma_f32_16x16x32_f16(a[kk][mt], bfrag[u][kk], acc[mt][u], 0, 0, 0);
        }

        f32x4 bv[4];
        #pragma unroll
        for (int mt = 0; mt < 4; ++mt)
            bv[mt] = *(const f32x4*)&b4_s[64 * c + 16 * mt + 4 * g];

        #pragma unroll
        for (int u = 0; u < 2; ++u) {
            float s = 0.f;
            #pragma unroll
            for (int mt = 0; mt < 4; ++mt)
                #pragma unroll
                for (int q = 0; q < 4; ++q)
                    s += (acc[mt][u][q] + bv[mt][q]) * hidr[u][mt][q];
            s += __shfl_xor(s, 16);
            s += __shfl_xor(s, 32);
            if (g == 0) res_s[(32 * rs + 16 * u + lr) * 12 + (c - 65)] = s;
        }
    }
    __syncthreads();

    // ---------------- chunk 75: out_b (rows 4800..4809)
    if (cw == 3) {
        const f16* Ab = W4h + (size_t)4800 * 128;
        f16x8 a[4];
        #pragma unroll
        for (int kk = 0; kk < 4; ++kk)
            a[kk] = *(const f16x8*)&Ab[lr * 128 + 32 * kk + 8 * g];
        #pragma unroll
        for (int u = 0; u < 2; ++u) {
            f32x4 acc = zero;
            #pragma unroll
            for (int kk = 0; kk < 4; ++kk)
                acc = __builtin_amdgcn_mfma_f32_16x16x32_f16(a[kk], bfrag[u][kk], acc, 0, 0, 0);
            const int si = 32 * rs + 16 * u + lr;
            #pragma unroll
            for (int q = 0; q < 4; ++q) {
                const int o = 4 * g + q;
                if (o < 10)
                    res_s[si * 12 + o] += acc[q] + b4_s[4800 + o];
            }
        }
    }
    __syncthreads();

    for (int e = t; e < 640; e += 512)
        out[(size_t)row0 * 10 + e] = res_s[(e / 10) * 12 + (e % 10)];
}

// ---------------------------------------------------------------- launcher
extern "C" void kernel_launch(void* const* d_in, const int* in_sizes, int n_in,
                              void* d_out, int out_size, void* d_ws, size_t ws_size,
                              hipStream_t stream)
{
    const float* data = (const float*)d_in[0];
    const int*   midx = (const int*)d_in[1];
    const float* W1   = (const float*)d_in[2];
    const float* b1   = (const float*)d_in[3];
    const float* W2   = (const float*)d_in[4];
    const float* b2   = (const float*)d_in[5];
    const float* W3   = (const float*)d_in[6];
    const float* b3   = (const float*)d_in[7];
    const float* W4   = (const float*)d_in[8];
    const float* b4   = (const float*)d_in[9];
    float* out = (float*)d_out;

    float* W1T   = (float*)d_ws;                        // 262144 f32
    float* xm_ws = W1T + 4096 * 64;                     // 1048576 f32
    f16*   h1h   = (f16*)(xm_ws + (size_t)16384 * 64);  // 1048576 f16
    f16*   W4h   = h1h + (size_t)16384 * 64;            // 622592 f16
    f16*   W2h   = W4h + (size_t)NPAD * 128;            // 16384 f16
    f16*   W3h   = W2h + 256 * 64;                      // 32768 f16

    k_prep  <<<512, 256, 0, stream>>>(W1, W2, W3, W4, W1T, W2h, W3h, W4h);
    k_gather<<<2048, 256, 0, stream>>>(data, midx, W1T, b1, xm_ws, h1h);
    k_hyper <<<256, 512, 0, stream>>>(xm_ws, h1h, W2h, b2, W3h, b3, W4h, b4, out);
}